// Round 15
// baseline (2137.742 us; speedup 1.0000x reference)
//
#include <hip/hip_runtime.h>
#include <math.h>

#define T_LEN 512
#define BATCH 128
#define KTAG  32
#define START_TAG 30
#define END_TAG   31
#define NEGV  -100000.0f

#define L2E    1.4426950408889634f
#define TWOL2E 2.8853900817779268f
#define LN2    0.6931471805599453f

typedef __attribute__((ext_vector_type(4))) short bf16x4;
typedef __attribute__((ext_vector_type(8))) short bf16x8;
typedef __attribute__((ext_vector_type(4))) float f32x4;
#define MFMA16   __builtin_amdgcn_mfma_f32_16x16x32_bf16
#define MFMA16F8 __builtin_amdgcn_mfma_f32_16x16x32_fp8_fp8
#define EXP2(x)  __builtin_amdgcn_exp2f(x)
#define RCP(x)   __builtin_amdgcn_rcpf(x)

__device__ __forceinline__ short f2bf(float x) {   // RNE fp32->bf16
    unsigned int u = __float_as_uint(x);
    u += 0x7fffu + ((u >> 16) & 1u);
    return (short)(u >> 16);
}

__device__ __forceinline__ f32x4 bf4_to_f32x4(bf16x4 v) {
    union { bf16x4 s; uint2 u; } c; c.s = v;
    f32x4 r;
    r[0] = __uint_as_float(c.u.x << 16);
    r[1] = __uint_as_float(c.u.x & 0xffff0000u);
    r[2] = __uint_as_float(c.u.y << 16);
    r[3] = __uint_as_float(c.u.y & 0xffff0000u);
    return r;
}

// fp32 -> OCP e4m3fn, RNE, saturate. (HW-verified round 5.)
__device__ __forceinline__ unsigned char f2fp8(float x) {
    unsigned u = __float_as_uint(x);
    unsigned s = (u >> 24) & 0x80u;
    unsigned mag = u & 0x7fffffffu;
    if (mag >= 0x43e80000u) return (unsigned char)(s | 0x7e);
    int e = (int)(mag >> 23) - 127;
    int ulp_exp = (e < -6) ? -9 : (e - 3);
    float C = __uint_as_float((unsigned)((ulp_exp + 23 + 127) << 23)) * 1.5f;
    float r = (__uint_as_float(mag) + C) - C;
    unsigned ru = __float_as_uint(r);
    int re = (int)(ru >> 23) - 127;
    unsigned code;
    if (r == 0.0f) code = 0;
    else if (re < -6) code = (unsigned)(r * 512.0f);
    else code = (unsigned)((re + 7) << 3) | ((ru >> 20) & 7u);
    return (unsigned char)(s | code);
}

__device__ __forceinline__ unsigned pack2_fp8(float h0, float h1) {
#if __has_builtin(__builtin_amdgcn_cvt_pk_fp8_f32)
    return (unsigned)__builtin_amdgcn_cvt_pk_fp8_f32(h0, h1, 0, false);
#else
    return (unsigned)f2fp8(h0) | ((unsigned)f2fp8(h1) << 8);
#endif
}

__global__ void fill_kernel(float* out, int n, float v) {
    int i = blockIdx.x * 256 + threadIdx.x;
    if (i < n) out[i] = v;
}

// ---------------------------------------------------------------------------
// Pack helpers (HW-verified rounds 3-14; log2-domain gate scaling).
// ---------------------------------------------------------------------------
__device__ __forceinline__ void dev_pack_bf16(const float* __restrict__ W,
                                              short* __restrict__ out, int K, int idx) {
    const int KT = K >> 5;
    int i  = idx & 7;
    int ln = (idx >> 3) & 63;
    int rem = idx >> 9;
    int kt = rem % KT;
    int wt = rem / KT;
    int type = wt & 3, w = wt >> 2;
    int row = type * 256 + w * 16 + (ln & 15);
    int col = kt * 32 + ((ln >> 4) << 3) + i;
    float sc = (type == 2) ? TWOL2E : L2E;
    out[idx] = f2bf(W[(size_t)row * K + col] * sc);
}

__device__ __forceinline__ void dev_pack_fp8(const float* __restrict__ W,
                                             unsigned char* __restrict__ out, int K, int idx) {
    const int KT = K >> 5;
    int i  = idx & 7;
    int ln = (idx >> 3) & 63;
    int rem = idx >> 9;
    int kt = rem % KT;
    int wt = rem / KT;
    int type = wt & 3, w = wt >> 2;
    int row = type * 256 + w * 16 + (ln & 15);
    int col = kt * 32 + ((ln >> 4) << 3) + i;
    float sc = (type == 2) ? TWOL2E : L2E;
    out[idx] = f2fp8(W[(size_t)row * K + col] * sc);
}

__device__ __forceinline__ void dev_pack_wtag(const float* __restrict__ Wtag,
                                              unsigned char* __restrict__ out, int idx) {
    int i  = idx & 7;
    int ln = (idx >> 3) & 63;
    int kt = (idx >> 9) & 7;
    int nt = (idx >> 12) & 1;
    int dir = idx >> 13;
    int row = nt * 16 + (ln & 15);
    int col = dir * 256 + kt * 32 + ((ln >> 4) << 3) + i;
    out[idx] = f2fp8(Wtag[row * 512 + col]);
}

__global__ __launch_bounds__(256) void pack_all(
    const float* Wih0f, const float* Wih0b, const float* Wih1f, const float* Wih1b,
    const float* Whh0f, const float* Whh0b, const float* Whh1f, const float* Whh1b,
    const float* Wtag, const float* emb,
    short* wq0f, short* wq0b, unsigned char* wq1f8, unsigned char* wq1b8,
    unsigned char* h80f, unsigned char* h80b, unsigned char* h81f, unsigned char* h81b,
    unsigned char* wtag8, short* embq)
{
    const int bx = blockIdx.x;
    const int tid = threadIdx.x;
    if (bx < 2048) {
        const float* W = (bx < 1024) ? Wih0f : Wih0b;
        short* o = (bx < 1024) ? wq0f : wq0b;
        dev_pack_bf16(W, o, 256, (bx & 1023) * 256 + tid);
    } else if (bx < 6144) {
        const float* W = (bx < 4096) ? Wih1f : Wih1b;
        unsigned char* o = (bx < 4096) ? wq1f8 : wq1b8;
        dev_pack_fp8(W, o, 512, ((bx - 2048) & 2047) * 256 + tid);
    } else if (bx < 10240) {
        int seg = (bx - 6144) >> 10;
        const float* W = (seg == 0) ? Whh0f : (seg == 1) ? Whh0b : (seg == 2) ? Whh1f : Whh1b;
        unsigned char* o = (seg == 0) ? h80f : (seg == 1) ? h80b : (seg == 2) ? h81f : h81b;
        dev_pack_fp8(W, o, 256, ((bx - 6144) & 1023) * 256 + tid);
    } else if (bx < 10304) {
        dev_pack_wtag(Wtag, wtag8, (bx - 10240) * 256 + tid);
    } else {
        int i = (bx - 10304) * 256 + tid;
        embq[i] = f2bf(emb[i]);
    }
}

// ---------------------------------------------------------------------------
// Gemm role (HW-verified r9-14). LAYER 0: bf16 NT=2. LAYER 1: fp8 A/B NT=2.
// ---------------------------------------------------------------------------
template <int LAYER, int AMODE>
__device__ __forceinline__ void gemm_role(
    int gb, int C, const int* __restrict__ words, const void* __restrict__ Asrc,
    const void* __restrict__ BfF, const void* __restrict__ BfB,
    const float* __restrict__ bsF, const float* __restrict__ bsB,
    short* __restrict__ preF, short* __restrict__ preB, int s0, char* smraw)
{
    constexpr int K  = (LAYER == 0) ? 256 : 512;
    constexpr int KT = K / 32;
    constexpr int RB = (LAYER == 0) ? K * 2 : K;
    constexpr int NT = 2;
    constexpr int NH = 2;

    const int dir = gb / (NH * C);
    int rem = gb - dir * NH * C;
    const int half = rem / C;
    const int gx = rem - half * C;
    const int sblk = gx >> 3, bg = gx & 7;
    const int t0 = half * NT;
    const int tid = threadIdx.x;
    const int wv = tid >> 6, L = tid & 63;
    const int wid = wv;
    const int brow = L & 15, kgrp = L >> 4;

    const void* Bf = dir ? BfB : BfF;
    const float* bias = dir ? bsB : bsF;
    short* pre = dir ? preB : preF;
    char* lds = smraw;

    bf16x8 bw16[LAYER == 0 ? NT * KT : 1][1];
    long   bw8[LAYER == 1 ? NT * KT : 1];
    if (LAYER == 0) {
        const bf16x8* Bp = (const bf16x8*)Bf;
#pragma unroll
        for (int u = 0; u < NT; ++u)
#pragma unroll
            for (int kt = 0; kt < KT; ++kt)
                bw16[u * KT + kt][0] = Bp[(((wid * 4 + t0 + u) * KT + kt) << 6) + L];
    } else {
        const long* Bp = (const long*)Bf;
#pragma unroll
        for (int u = 0; u < NT; ++u)
#pragma unroll
            for (int kt = 0; kt < KT; ++kt)
                bw8[u * KT + kt] = Bp[(((wid * 4 + t0 + u) * KT + kt) << 6) + L];
    }

    float bb[NT];
#pragma unroll
    for (int u = 0; u < NT; ++u) {
        float sc = ((t0 + u) == 2) ? TWOL2E : L2E;
        bb[u] = bias[(t0 + u) * 256 + wid * 16 + brow] * sc;
    }

    for (int sl = 0; sl < 8; ++sl) {
        const int sloc = sblk * 8 + sl;
        const int t = dir ? (T_LEN - 1 - (s0 + sloc)) : (s0 + sloc);

        if (LAYER == 0) {
            if (tid < 512) {
                const int row = tid >> 5, ch = tid & 31;
                const int b = bg * 16 + row;
                const int cb = ch * 16;
                const int word = words[b * T_LEN + t];
                if (AMODE == 0) {
                    const char* src = (const char*)Asrc + (size_t)word * 512 + cb;
                    *(bf16x8*)(lds + ((row * RB + cb) ^ ((row & 7) << 4))) = *(const bf16x8*)src;
                } else {
                    const float* src = (const float*)Asrc + (size_t)word * 256 + ch * 8;
                    float4 f0 = *(const float4*)(src);
                    float4 f1 = *(const float4*)(src + 4);
                    short tmp[8] = {f2bf(f0.x), f2bf(f0.y), f2bf(f0.z), f2bf(f0.w),
                                    f2bf(f1.x), f2bf(f1.y), f2bf(f1.z), f2bf(f1.w)};
                    *(bf16x8*)(lds + ((row * RB + cb) ^ ((row & 7) << 4))) = *(const bf16x8*)tmp;
                }
            }
        } else {
            const int row = tid >> 6, ch = tid & 63;
            const int b = bg * 16 + row;
            const int cb = ch * 8;
            const unsigned char* src = (const unsigned char*)Asrc +
                                       ((size_t)t * BATCH + b) * 512 + cb;
            *(long*)(lds + ((row * RB + cb) ^ ((row & 7) << 3))) = *(const long*)src;
        }
        __syncthreads();

        f32x4 acc[NT];
#pragma unroll
        for (int u = 0; u < NT; ++u) acc[u] = (f32x4){bb[u], bb[u], bb[u], bb[u]};

#pragma unroll
        for (int kt = 0; kt < KT; ++kt) {
            if (LAYER == 0) {
                bf16x8 a = *(const bf16x8*)(lds + ((brow * RB + kt * 64 + kgrp * 16) ^ ((brow & 7) << 4)));
#pragma unroll
                for (int u = 0; u < NT; ++u)
                    acc[u] = MFMA16(a, bw16[u * KT + kt][0], acc[u], 0, 0, 0);
            } else {
                long a = *(const long*)(lds + ((brow * RB + kt * 32 + kgrp * 8) ^ ((brow & 7) << 3)));
#pragma unroll
                for (int u = 0; u < NT; ++u)
                    acc[u] = MFMA16F8(a, bw8[u * KT + kt], acc[u], 0, 0, 0);
            }
        }

        bf16x4* pp = (bf16x4*)pre;
        const size_t base = ((((size_t)sloc * 8 + bg) * 16 + wid) * 4 + t0) * 64 + L;
#pragma unroll
        for (int u = 0; u < NT; ++u) {
            bf16x4 o = {f2bf(acc[u][0]), f2bf(acc[u][1]), f2bf(acc[u][2]), f2bf(acc[u][3])};
            pp[base + (size_t)u * 64] = o;
        }
        __syncthreads();
    }
}

__global__ __launch_bounds__(1024) void gemm_only0(
    const int* words, const void* Asrc, const void* BfF, const void* BfB,
    const float* bsF, const float* bsB, short* preF, short* preB, int s0, int C, int amode)
{
    __shared__ __align__(16) char smraw[8192];
    if (amode == 0)
        gemm_role<0, 0>(blockIdx.x, C, words, Asrc, BfF, BfB, bsF, bsB, preF, preB, s0, smraw);
    else
        gemm_role<0, 1>(blockIdx.x, C, words, Asrc, BfF, BfB, bsF, bsB, preF, preB, s0, smraw);
}

__global__ __launch_bounds__(1024) void gemm_only1(
    const int* words, const void* Asrc, const void* BfF, const void* BfB,
    const float* bsF, const float* bsB, short* preF, short* preB, int s0, int C)
{
    __shared__ __align__(16) char smraw[8192];
    gemm_role<1, 2>(blockIdx.x, C, words, Asrc, BfF, BfB, bsF, bsB, preF, preB, s0, smraw);
}

// ---------------------------------------------------------------------------
// Fused chunk (HW-verified r9-14): blocks 0-31 = LSTM (M=8, split-layout,
// setprio(1)), blocks 32+ = pregate gemm for next chunk.
// Round 15: gate MFMA chain split 2x4-deep (accA+accB) to cut chain latency.
// ---------------------------------------------------------------------------
template <int LAYER, int AMODE>
__global__ __launch_bounds__(1024) void fused_chunk(
    const int* __restrict__ words, const void* __restrict__ xsrc,
    const void* __restrict__ wihF, const void* __restrict__ wihB,
    const float* __restrict__ biasF, const float* __restrict__ biasB,
    short* __restrict__ preOutF, short* __restrict__ preOutB, int s0g, int gemm_on,
    const short* __restrict__ preF, const short* __restrict__ preB,
    const unsigned char* __restrict__ whhF, const unsigned char* __restrict__ whhB,
    unsigned char* __restrict__ h1out,
    const unsigned char* __restrict__ wtagf, const float* __restrict__ btag,
    float* __restrict__ emitF, float* __restrict__ emitB,
    float* __restrict__ stC, long* __restrict__ stH,
    int s0, int C)
{
    constexpr int SMB = (LAYER == 1) ? (8704 + 32768) : 8704;
    __shared__ __align__(16) char smraw[SMB];

    if (blockIdx.x >= 32) {
        if (gemm_on)
            gemm_role<LAYER, AMODE>(blockIdx.x - 32, C, words, xsrc, wihF, wihB,
                                    biasF, biasB, preOutF, preOutB, s0g, smraw);
        return;
    }

    // lstm waves carry the serial dependency chain: boost their CU priority
    __builtin_amdgcn_s_setprio(1);

    const int dir  = blockIdx.x >> 4;
    const int bg   = (blockIdx.x >> 1) & 7;
    const int half = blockIdx.x & 1;
    const int tid = threadIdx.x;
    const int wid = tid >> 6;
    const int L   = tid & 63;
    const int brow = L & 15;
    const int kgrp = L >> 4;
    const int Lp = (L + half * 32) & 63;

    const bf16x4* pre = (const bf16x4*)(dir ? preB : preF);
    long* hb0 = (long*)smraw;
    long* hb1 = (long*)(smraw + 4352);
    float (*ep)[8][16][32] = (float(*)[8][16][32])(smraw + 8704);

    const long* Wp = (const long*)(dir ? whhB : whhF);
    long whh[32];
#pragma unroll
    for (int tt = 0; tt < 4; ++tt)
#pragma unroll
        for (int kt = 0; kt < 8; ++kt)
            whh[tt * 8 + kt] = Wp[(((wid * 4 + tt) * 8 + kt) << 6) + L];

    long wt0 = 0, wt1 = 0;
    if (LAYER == 1) {
        int kw = (wid < 8) ? wid : 7;
        const long* wtp = (const long*)wtagf;
        wt0 = wtp[(((dir * 2 + 0) * 8 + kw) << 6) + L];
        wt1 = wtp[(((dir * 2 + 1) * 8 + kw) << 6) + L];
    }

    float cs0, cs1;
    if (s0 == 0) {
        for (int q = tid; q < 544; q += 1024) hb0[q] = 0;
        cs0 = cs1 = 0.f;
    } else {
        for (int q = tid; q < 544; q += 1024)
            hb0[q] = stH[(size_t)blockIdx.x * 544 + q];
        float2 c2 = ((const float2*)stC)[blockIdx.x * 1024 + tid];
        cs0 = c2.x; cs1 = c2.y;
    }
    for (int q = tid; q < 544; q += 1024) hb1[q] = 0;
    __syncthreads();

    const size_t pstride = 8 * 16 * 4 * 64;
    const size_t pbase = (((size_t)bg * 16 + wid) * 4) * 64 + Lp;
    bf16x4 pc0 = pre[pbase + 0 * 64];
    bf16x4 pc1 = pre[pbase + 1 * 64];
    bf16x4 pc2 = pre[pbase + 2 * 64];
    bf16x4 pc3 = pre[pbase + 3 * 64];

    const int srcL = L & 31;
    const bool lo = (L < 32);
    const int rb = ((srcL >> 4) << 2) + (lo ? 0 : 2);
    const int jj = wid * 16 + (L & 15);

    for (int s = s0; s < s0 + C; ++s) {
        const int sloc = s - s0;
        const int par = s & 1;
        const char* ldsr = (const char*)(par ? hb1 : hb0);
        char* ldsw = (char*)(par ? hb0 : hb1);

        f32x4 acc0 = bf4_to_f32x4(pc0);
        f32x4 acc1 = bf4_to_f32x4(pc1);
        f32x4 acc2 = bf4_to_f32x4(pc2);
        f32x4 acc3 = bf4_to_f32x4(pc3);
        f32x4 ab0 = {0.f, 0.f, 0.f, 0.f};
        f32x4 ab1 = {0.f, 0.f, 0.f, 0.f};
        f32x4 ab2 = {0.f, 0.f, 0.f, 0.f};
        f32x4 ab3 = {0.f, 0.f, 0.f, 0.f};

        {
            const int sl2 = (sloc + 1 < C) ? sloc + 1 : sloc;
            const size_t pb = (size_t)sl2 * pstride + pbase;
            pc0 = pre[pb + 0 * 64];
            pc1 = pre[pb + 1 * 64];
            pc2 = pre[pb + 2 * 64];
            pc3 = pre[pb + 3 * 64];
        }

        // gate MFMAs: two independent 4-deep chains per gate (latency cut)
#pragma unroll
        for (int kt = 0; kt < 4; ++kt) {
            long a = *(const long*)(ldsr + brow * 272 + kt * 32 + kgrp * 8);
            long a2 = *(const long*)(ldsr + brow * 272 + (kt + 4) * 32 + kgrp * 8);
            acc0 = MFMA16F8(a, whh[0 * 8 + kt], acc0, 0, 0, 0);
            acc1 = MFMA16F8(a, whh[1 * 8 + kt], acc1, 0, 0, 0);
            acc2 = MFMA16F8(a, whh[2 * 8 + kt], acc2, 0, 0, 0);
            acc3 = MFMA16F8(a, whh[3 * 8 + kt], acc3, 0, 0, 0);
            ab0 = MFMA16F8(a2, whh[0 * 8 + kt + 4], ab0, 0, 0, 0);
            ab1 = MFMA16F8(a2, whh[1 * 8 + kt + 4], ab1, 0, 0, 0);
            ab2 = MFMA16F8(a2, whh[2 * 8 + kt + 4], ab2, 0, 0, 0);
            ab3 = MFMA16F8(a2, whh[3 * 8 + kt + 4], ab3, 0, 0, 0);
        }
        acc0 += ab0; acc1 += ab1; acc2 += ab2; acc3 += ab3;

        if (LAYER == 1 && sloc >= 1 && wid < 8) {
            long a = *(const long*)(ldsr + brow * 272 + wid * 32 + kgrp * 8);
            f32x4 e0 = {0.f, 0.f, 0.f, 0.f}, e1 = {0.f, 0.f, 0.f, 0.f};
            e0 = MFMA16F8(a, wt0, e0, 0, 0, 0);
            e1 = MFMA16F8(a, wt1, e1, 0, 0, 0);
#pragma unroll
            for (int r = 0; r < 4; ++r) {
                int bl = (kgrp << 2) + r;
                ep[par][wid][bl][brow] = e0[r];
                ep[par][wid][bl][16 + brow] = e1[r];
            }
        }

        if (LAYER == 1 && sloc >= 2 && tid < 256) {
            int bl = tid >> 5, tg = tid & 31;
            float v = 0.f;
#pragma unroll
            for (int p = 0; p < 8; ++p) v += ep[par ^ 1][p][bl][tg];
            const int x = s - 2;
            const int tp = dir ? (T_LEN - 1 - x) : x;
            size_t ei = ((size_t)tp * BATCH + bg * 16 + half * 8 + bl) * KTAG + tg;
            if (dir == 0) emitF[ei] = v + btag[tg];
            else          emitB[ei] = v;
        }

        float g0v0, g0v1, g1v0, g1v1, g2v0, g2v1, g3v0, g3v1;
        {
            float a00 = __shfl(acc0[2], srcL), a01 = __shfl(acc0[3], srcL);
            float a10 = __shfl(acc1[2], srcL), a11 = __shfl(acc1[3], srcL);
            float a20 = __shfl(acc2[2], srcL), a21 = __shfl(acc2[3], srcL);
            float a30 = __shfl(acc3[2], srcL), a31 = __shfl(acc3[3], srcL);
            g0v0 = lo ? acc0[0] : a00;  g0v1 = lo ? acc0[1] : a01;
            g1v0 = lo ? acc1[0] : a10;  g1v1 = lo ? acc1[1] : a11;
            g2v0 = lo ? acc2[0] : a20;  g2v1 = lo ? acc2[1] : a21;
            g3v0 = lo ? acc3[0] : a30;  g3v1 = lo ? acc3[1] : a31;
        }

        float hh0, hh1;
        {
            float ig, fg, gg, og;
            ig = RCP(1.0f + EXP2(-g0v0)); fg = RCP(1.0f + EXP2(-g1v0));
            gg = 1.0f - 2.0f * RCP(1.0f + EXP2(g2v0));
            og = RCP(1.0f + EXP2(-g3v0));
            cs0 = fg * cs0 + ig * gg;
            hh0 = og * (1.0f - 2.0f * RCP(1.0f + EXP2(TWOL2E * cs0)));
            ig = RCP(1.0f + EXP2(-g0v1)); fg = RCP(1.0f + EXP2(-g1v1));
            gg = 1.0f - 2.0f * RCP(1.0f + EXP2(g2v1));
            og = RCP(1.0f + EXP2(-g3v1));
            cs1 = fg * cs1 + ig * gg;
            hh1 = og * (1.0f - 2.0f * RCP(1.0f + EXP2(TWOL2E * cs1)));
        }

        {
            unsigned pk = pack2_fp8(hh0, hh1);
            ldsw[(rb + 0) * 272 + jj] = (char)(pk);
            ldsw[(rb + 1) * 272 + jj] = (char)(pk >> 8);
            if (LAYER == 0) {
                const int t = dir ? (T_LEN - 1 - s) : s;
                size_t gb = ((size_t)t * BATCH + bg * 16 + half * 8 + rb) * 512 + dir * 256 + jj;
                h1out[gb]       = (unsigned char)pk;
                h1out[gb + 512] = (unsigned char)(pk >> 8);
            }
        }
        __syncthreads();
    }

    if (LAYER == 1) {
        if (wid < 8) {
            const char* ldsr = (const char*)hb0;
            long a = *(const long*)(ldsr + brow * 272 + wid * 32 + kgrp * 8);
            f32x4 e0 = {0.f, 0.f, 0.f, 0.f}, e1 = {0.f, 0.f, 0.f, 0.f};
            e0 = MFMA16F8(a, wt0, e0, 0, 0, 0);
            e1 = MFMA16F8(a, wt1, e1, 0, 0, 0);
#pragma unroll
            for (int r = 0; r < 4; ++r) {
                int bl = (kgrp << 2) + r;
                ep[0][wid][bl][brow] = e0[r];
                ep[0][wid][bl][16 + brow] = e1[r];
            }
        }
        if (tid < 256) {
            int bl = tid >> 5, tg = tid & 31;
            float v = 0.f;
#pragma unroll
            for (int p = 0; p < 8; ++p) v += ep[1][p][bl][tg];
            const int x = s0 + C - 2;
            const int tp = dir ? (T_LEN - 1 - x) : x;
            size_t ei = ((size_t)tp * BATCH + bg * 16 + half * 8 + bl) * KTAG + tg;
            if (dir == 0) emitF[ei] = v + btag[tg];
            else          emitB[ei] = v;
        }
        __syncthreads();
        if (tid < 256) {
            int bl = tid >> 5, tg = tid & 31;
            float v = 0.f;
#pragma unroll
            for (int p = 0; p < 8; ++p) v += ep[0][p][bl][tg];
            const int x = s0 + C - 1;
            const int tp = dir ? (T_LEN - 1 - x) : x;
            size_t ei = ((size_t)tp * BATCH + bg * 16 + half * 8 + bl) * KTAG + tg;
            if (dir == 0) emitF[ei] = v + btag[tg];
            else          emitB[ei] = v;
        }
    }

    for (int q = tid; q < 544; q += 1024)
        stH[(size_t)blockIdx.x * 544 + q] = hb0[q];
    ((float2*)stC)[blockIdx.x * 1024 + tid] = (float2){cs0, cs1};
    __builtin_amdgcn_s_setprio(0);
}

// ---------------------------------------------------------------------------
// CRF (HW-verified rounds 12-14): forward-backward split, 4 roles x 128.
// ---------------------------------------------------------------------------
__global__ __launch_bounds__(64) void crf_half(
    const float* __restrict__ emitF, const float* __restrict__ emitB,
    const float* __restrict__ trans,
    float* __restrict__ alph, float* __restrict__ betap,
    float* __restrict__ alphV, float* __restrict__ betaV,
    unsigned char* __restrict__ bpsW, unsigned char* __restrict__ npsW)
{
    const int lane = threadIdx.x;
    const int k = lane & 31;
    const int h = lane >> 5;
    const int p0 = h << 4;
    const int role = blockIdx.x >> 7;
    const int b = blockIdx.x & 127;

    __shared__ unsigned char ptr_l[256 * KTAG];

    if (role == 0) {
        float trow2[16];
#pragma unroll
        for (int i = 0; i < 4; ++i) {
            float4 f = *(const float4*)(trans + k * KTAG + p0 + i * 4);
            trow2[i * 4 + 0] = f.x * L2E; trow2[i * 4 + 1] = f.y * L2E;
            trow2[i * 4 + 2] = f.z * L2E; trow2[i * 4 + 3] = f.w * L2E;
        }
        float dp = (k == START_TAG) ? 0.0f : NEGV * L2E;
        size_t e0i = (size_t)b * KTAG + k;
        float e2 = (emitF[e0i] + emitB[e0i]) * L2E;

        for (int t = 0; t < 256; ++t) {
            float e_next2 = 0.0f;
            if (t + 1 < 256) {
                size_t ei = ((size_t)(t + 1) * BATCH + b) * KTAG + k;
                e_next2 = (emitF[ei] + emitB[ei]) * L2E;
            }
            float v[16];
#pragma unroll
            for (int q = 0; q < 16; ++q)
                v[q] = trow2[q] + __shfl(dp, p0 + q);
            float mx[8];
#pragma unroll
            for (int i = 0; i < 8; ++i) mx[i] = fmaxf(v[i], v[i + 8]);
#pragma unroll
            for (int i = 0; i < 4; ++i) mx[i] = fmaxf(mx[i], mx[i + 4]);
            float halfm = fmaxf(fmaxf(mx[0], mx[1]), fmaxf(mx[2], mx[3]));
            float m = fmaxf(halfm, __shfl_xor(halfm, 32));
            float es[16];
#pragma unroll
            for (int i = 0; i < 16; ++i) es[i] = EXP2(v[i] - m);
#pragma unroll
            for (int i = 0; i < 8; ++i) es[i] += es[i + 8];
#pragma unroll
            for (int i = 0; i < 4; ++i) es[i] += es[i + 4];
            float shalf = (es[0] + es[1]) + (es[2] + es[3]);
            float ssum = shalf + __shfl_xor(shalf, 32);
            dp = e2 + m + __log2f(ssum);
            e2 = e_next2;
        }
        if (lane < 32) alph[b * KTAG + k] = dp;
    } else if (role == 1) {
        float trowT2[16];
#pragma unroll
        for (int i = 0; i < 16; ++i)
            trowT2[i] = trans[(p0 + i) * KTAG + k] * L2E;
        float beta = trans[END_TAG * KTAG + k] * L2E;
        size_t e0i = ((size_t)511 * BATCH + b) * KTAG + k;
        float e2 = (emitF[e0i] + emitB[e0i]) * L2E;

        for (int it = 0; it < 256; ++it) {
            const int t = 510 - it;
            float e_next2 = 0.0f;
            if (it + 1 < 256) {
                size_t ei = ((size_t)t * BATCH + b) * KTAG + k;
                e_next2 = (emitF[ei] + emitB[ei]) * L2E;
            }
            float z = beta + e2;
            float v[16];
#pragma unroll
            for (int q = 0; q < 16; ++q)
                v[q] = trowT2[q] + __shfl(z, p0 + q);
            float mx[8];
#pragma unroll
            for (int i = 0; i < 8; ++i) mx[i] = fmaxf(v[i], v[i + 8]);
#pragma unroll
            for (int i = 0; i < 4; ++i) mx[i] = fmaxf(mx[i], mx[i + 4]);
            float halfm = fmaxf(fmaxf(mx[0], mx[1]), fmaxf(mx[2], mx[3]));
            float m = fmaxf(halfm, __shfl_xor(halfm, 32));
            float es[16];
#pragma unroll
            for (int i = 0; i < 16; ++i) es[i] = EXP2(v[i] - m);
#pragma unroll
            for (int i = 0; i < 8; ++i) es[i] += es[i + 8];
#pragma unroll
            for (int i = 0; i < 4; ++i) es[i] += es[i + 4];
            float shalf = (es[0] + es[1]) + (es[2] + es[3]);
            float ssum = shalf + __shfl_xor(shalf, 32);
            beta = m + __log2f(ssum);
            e2 = e_next2;
        }
        if (lane < 32) betap[b * KTAG + k] = beta;
    } else if (role == 2) {
        float trow[16];
#pragma unroll
        for (int i = 0; i < 4; ++i) {
            float4 f = *(const float4*)(trans + k * KTAG + p0 + i * 4);
            trow[i * 4 + 0] = f.x; trow[i * 4 + 1] = f.y;
            trow[i * 4 + 2] = f.z; trow[i * 4 + 3] = f.w;
        }
        float dpv = (k == START_TAG) ? 0.0f : NEGV;
        size_t e0i = (size_t)b * KTAG + k;
        float e = emitF[e0i] + emitB[e0i];

        for (int t = 0; t < 256; ++t) {
            float e_next = 0.0f;
            if (t + 1 < 256) {
                size_t ei = ((size_t)(t + 1) * BATCH + b) * KTAG + k;
                e_next = emitF[ei] + emitB[ei];
            }
            float w[16];
#pragma unroll
            for (int q = 0; q < 16; ++q)
                w[q] = trow[q] + __shfl(dpv, p0 + q);
            float bv_[8]; int bi_[8];
#pragma unroll
            for (int i = 0; i < 8; ++i) {
                bool g = w[2 * i + 1] > w[2 * i];
                bv_[i] = g ? w[2 * i + 1] : w[2 * i];
                bi_[i] = p0 + (g ? 2 * i + 1 : 2 * i);
            }
#pragma unroll
            for (int i = 0; i < 4; ++i) {
                bool g = bv_[2 * i + 1] > bv_[2 * i];
                bv_[i] = g ? bv_[2 * i + 1] : bv_[2 * i];
                bi_[i] = g ? bi_[2 * i + 1] : bi_[2 * i];
            }
            { bool g = bv_[3] > bv_[2]; bv_[1] = g ? bv_[3] : bv_[2]; bi_[1] = g ? bi_[3] : bi_[2]; }
            { bool g = bv_[1] > bv_[0]; bv_[0] = g ? bv_[1] : bv_[0]; bi_[0] = g ? bi_[1] : bi_[0]; }
            float ov = __shfl_xor(bv_[0], 32);
            int   oi = __shfl_xor(bi_[0], 32);
            bool g2 = h ? (ov >= bv_[0]) : (ov > bv_[0]);
            float bm  = g2 ? ov : bv_[0];
            int  barg = g2 ? oi : bi_[0];
            dpv = e + bm;
            if (!h) ptr_l[t * KTAG + k] = (unsigned char)barg;
            e = e_next;
        }
        if (lane < 32) alphV[b * KTAG + k] = dpv;
        for (int i = lane; i < 2048; i += 64)
            ((unsigned*)bpsW)[(size_t)b * 2048 + i] = ((const unsigned*)ptr_l)[i];
    } else {
        float trowT[16];
#pragma unroll
        for (int i = 0; i < 16; ++i)
            trowT[i] = trans[(p0 + i) * KTAG + k];
        float bvv = trans[END_TAG * KTAG + k];
        size_t e0i = ((size_t)511 * BATCH + b) * KTAG + k;
        float e = emitF[e0i] + emitB[e0i];

        for (int it = 0; it < 256; ++it) {
            const int t = 510 - it;
            float e_next = 0.0f;
            if (it + 1 < 256) {
                size_t ei = ((size_t)t * BATCH + b) * KTAG + k;
                e_next = emitF[ei] + emitB[ei];
            }
            float z = bvv + e;
            float w[16];
#pragma unroll
            for (int q = 0; q < 16; ++q)
                w[q] = trowT[q] + __shfl(z, p0 + q);
            float bv_[8]; int bi_[8];
#pragma unroll
            for (int i = 0; i < 8; ++i) {
                bool g = w[2 * i + 1] > w[2 * i];
                bv_[i] = g ? w[2 * i + 1] : w[2 * i];
                bi_[i] = p0 + (g ? 2 * i + 1 : 2 * i);
            }
#pragma unroll
            for (int i = 0; i < 4; ++i) {
                bool g = bv_[2 * i + 1] > bv_[2 * i];
                bv_[i] = g ? bv_[2 * i + 1] : bv_[2 * i];
                bi_[i] = g ? bi_[2 * i + 1] : bi_[2 * i];
            }
            { bool g = bv_[3] > bv_[2]; bv_[1] = g ? bv_[3] : bv_[2]; bi_[1] = g ? bi_[3] : bi_[2]; }
            { bool g = bv_[1] > bv_[0]; bv_[0] = g ? bv_[1] : bv_[0]; bi_[0] = g ? bi_[1] : bi_[0]; }
            float ov = __shfl_xor(bv_[0], 32);
            int   oi = __shfl_xor(bi_[0], 32);
            bool g2 = h ? (ov >= bv_[0]) : (ov > bv_[0]);
            float bm  = g2 ? ov : bv_[0];
            int  barg = g2 ? oi : bi_[0];
            bvv = bm;
            if (!h) ptr_l[(t - 255) * KTAG + k] = (unsigned char)barg;
            e = e_next;
        }
        if (lane < 32) betaV[b * KTAG + k] = bvv;
        for (int i = lane; i < 2048; i += 64)
            ((unsigned*)npsW)[(size_t)b * 2048 + i] = ((const unsigned*)ptr_l)[i];
    }
}

__global__ __launch_bounds__(64) void crf_join(
    const float* __restrict__ emitF, const float* __restrict__ emitB,
    const float* __restrict__ trans, const int* __restrict__ labels,
    const float* __restrict__ alph, const float* __restrict__ betap,
    const float* __restrict__ alphV, const float* __restrict__ betaV,
    const unsigned char* __restrict__ bpsW, const unsigned char* __restrict__ npsW,
    float* __restrict__ diff, float* __restrict__ path_out)
{
    const int b = blockIdx.x;
    const int lane = threadIdx.x;
    const int k = lane & 31;

    __shared__ unsigned char bps_l[256 * KTAG];
    __shared__ unsigned char nps_l[256 * KTAG];
    __shared__ unsigned char pth[T_LEN];

    for (int i = lane; i < 2048; i += 64) {
        ((unsigned*)bps_l)[i] = ((const unsigned*)bpsW)[(size_t)b * 2048 + i];
        ((unsigned*)nps_l)[i] = ((const unsigned*)npsW)[(size_t)b * 2048 + i];
    }

    float fv = alph[b * KTAG + k] + betap[b * KTAG + k];
    float mm = fv;
    for (int off = 16; off; off >>= 1) mm = fmaxf(mm, __shfl_xor(mm, off));
    float contrib = (lane < KTAG) ? EXP2(fv - mm) : 0.0f;
    float ss = contrib;
    for (int off = 32; off; off >>= 1) ss += __shfl_xor(ss, off);
    float logZ = (mm + __log2f(ss)) * LN2;

    float gsum = 0.0f;
    for (int t = lane; t < T_LEN; t += 64) {
        int curl = labels[b * T_LEN + t];
        int prev = (t > 0) ? labels[b * T_LEN + t - 1] : START_TAG;
        size_t gi = ((size_t)t * BATCH + b) * KTAG + curl;
        gsum += trans[curl * KTAG + prev] + emitF[gi] + emitB[gi];
    }
    if (lane == 0) gsum += trans[END_TAG * KTAG + labels[b * T_LEN + T_LEN - 1]];
    for (int off = 32; off; off >>= 1) gsum += __shfl_xor(gsum, off);

    float av = alphV[b * KTAG + k] + betaV[b * KTAG + k];
    int bi = k;
    for (int off = 16; off; off >>= 1) {
        float ovv = __shfl_xor(av, off);
        int   oii = __shfl_xor(bi, off);
        if (ovv > av || (ovv == av && oii < bi)) { av = ovv; bi = oii; }
    }

    __syncthreads();
    if (lane == 0) {
        diff[b] = logZ - gsum;
        int pb = bi, pf = bi;
        pth[255] = (unsigned char)bi;
        for (int i = 1; i <= 256; ++i) {
            if (i <= 255) {
                pb = bps_l[(256 - i) * KTAG + pb];
                pth[255 - i] = (unsigned char)pb;
            }
            pf = nps_l[(i - 1) * KTAG + pf];
            pth[255 + i] = (unsigned char)pf;
        }
    }
    __syncthreads();
    for (int t = lane; t < T_LEN; t += 64)
        path_out[(size_t)b * T_LEN + t] = (float)pth[t];
}

__global__ void nll_kernel(const float* __restrict__ diff, float* __restrict__ out) {
    int lane = threadIdx.x;   // 128
    float v = diff[lane];
    __shared__ float red[2];
    for (int off = 32; off; off >>= 1) v += __shfl_xor(v, off);
    if ((lane & 63) == 0) red[lane >> 6] = v;
    __syncthreads();
    if (lane == 0) out[0] = (red[0] + red[1]) / 128.0f;
}

// ---------------------------------------------------------------------------
extern "C" void kernel_launch(void* const* d_in, const int* in_sizes, int n_in,
                              void* d_out, int out_size, void* d_ws, size_t ws_size,
                              hipStream_t stream) {
    (void)in_sizes; (void)n_in;

    const int*   words  = (const int*)d_in[0];
    const int*   labels = (const int*)d_in[1];
    const float* emb    = (const float*)d_in[2];
    const float* Wih0f  = (const float*)d_in[3];
    const float* Whh0f  = (const float*)d_in[4];
    const float* b0f    = (const float*)d_in[5];
    const float* Wih0b  = (const float*)d_in[6];
    const float* Whh0b  = (const float*)d_in[7];
    const float* b0b    = (const float*)d_in[8];
    const float* Wih1f  = (const float*)d_in[9];
    const float* Whh1f  = (const float*)d_in[10];
    const float* b1f    = (const float*)d_in[11];
    const float* Wih1b  = (const float*)d_in[12];
    const float* Whh1b  = (const float*)d_in[13];
    const float* b1b    = (const float*)d_in[14];
    const float* Wtag   = (const float*)d_in[15];
    const float* btag   = (const float*)d_in[16];
    const float* trans  = (const float*)d_in[17];
    float* out = (float*)d_out;
    char* ws = (char*)d_ws;

    const size_t WIH0B = (size_t)1024 * 256 * 2;            // 512 KB (bf16)
    const size_t WIH1B = (size_t)1024 * 512;                // 512 KB (fp8)
    const size_t WHH8B = (size_t)1024 * 256;                // 256 KB
    const size_t WTAG8 = (size_t)16384;                     // 16 KB
    const size_t H1B   = (size_t)T_LEN * BATCH * 512;       // 33.6 MB (fp8)
    const size_t EMITB = (size_t)T_LEN * BATCH * KTAG * 4;  // 8.39 MB
    const size_t EMBQB = (size_t)30000 * 256 * 2;           // 15.36 MB
    const size_t STHB  = (size_t)32 * 544 * 8;              // 139 KB
    const size_t STCB  = (size_t)32 * 1024 * 8;             // 256 KB
    const size_t PSTEP = (size_t)BATCH * 1024 * 2;          // 0.262 MB/step/dir
    const size_t CRFAB = (size_t)4 * 128 * 32 * 4;          // 64 KB
    const size_t BPSB  = (size_t)128 * 256 * 32;            // 1 MB each

    const size_t base0 = 2 * WIH0B + 2 * WIH1B + 4 * WHH8B + WTAG8 + H1B +
                         2 * EMITB + STHB + STCB + CRFAB + 2 * BPSB +
                         4096 + (1u << 20);

    // C=256 verified fastest per-step (round 13/14 A-B); largest-fit search.
    int C = 0, use_embq = 0;
    for (int eq = 1; eq >= 0 && !C; --eq)
        for (int c = 256; c >= 16 && !C; c >>= 1)
            if (base0 + (eq ? EMBQB : 0) + 4 * (size_t)c * PSTEP <= ws_size) {
                C = c; use_embq = eq;
            }
    if (!C) {
        fill_kernel<<<(out_size + 255) / 256, 256, 0, stream>>>(
            out, out_size, (float)(ws_size >> 20));
        return;
    }

    size_t off = 0;
    auto alloc = [&](size_t bytes) -> char* {
        char* p = ws + off;
        off = (off + bytes + 255) & ~(size_t)255;
        return p;
    };
    short* wihq0f = (short*)alloc(WIH0B);
    short* wihq0b = (short*)alloc(WIH0B);
    unsigned char* wihq1f8 = (unsigned char*)alloc(WIH1B);
    unsigned char* wihq1b8 = (unsigned char*)alloc(WIH1B);
    unsigned char* whh8_0f = (unsigned char*)alloc(WHH8B);
    unsigned char* whh8_0b = (unsigned char*)alloc(WHH8B);
    unsigned char* whh8_1f = (unsigned char*)alloc(WHH8B);
    unsigned char* whh8_1b = (unsigned char*)alloc(WHH8B);
    unsigned char* wtag8   = (unsigned char*)alloc(WTAG8);
    unsigned char* h1      = (unsigned char*)alloc(H1B);
    float* emF    = (float*)alloc(EMITB);
    float* emB    = (float*)alloc(EMITB);
    long*  stH    = (long*)alloc(STHB);
    float* stC    = (float*)alloc(STCB);
    float* diff   = (float*)alloc(4096);
    float* crfa   = (float*)alloc(CRFAB);
    unsigned char* bpsW = (unsigned char*)alloc(BPSB);
    unsigned char* npsW = (unsigned char*)alloc(BPSB);
    short* preFb[2], * preBb[2];
    preFb[0] = (short*)alloc((size_t)C * PSTEP);
    preFb[1] = (short*)alloc((size_t)C * PSTEP);
    preBb[0] = (short*)alloc((size_t)C * PSTEP);
    preBb[1] = (short*)alloc((size_t)C * PSTEP);
    short* embq = use_embq ? (short*)alloc(EMBQB) : nullptr;

    float* alph  = crfa;
    float* betap = crfa + 128 * 32;
    float* alphV = crfa + 2 * 128 * 32;
    float* betaV = crfa + 3 * 128 * 32;

    // ---- single pack launch ----
    {
        int nblk = 10304 + (use_embq ? 30000 : 0);
        pack_all<<<nblk, 256, 0, stream>>>(
            Wih0f, Wih0b, Wih1f, Wih1b, Whh0f, Whh0b, Whh1f, Whh1b, Wtag, emb,
            wihq0f, wihq0b, wihq1f8, wihq1b8,
            whh8_0f, whh8_0b, whh8_1f, whh8_1b, wtag8, embq);
    }

    const int NC = T_LEN / C;
    const void* xsrc0 = use_embq ? (const void*)embq : (const void*)emb;
    const int am = use_embq ? 0 : 1;

    // ---- layer 0 ----
    gemm_only0<<<4 * C, 1024, 0, stream>>>(words, xsrc0, wihq0f, wihq0b,
                                           b0f, b0b, preFb[0], preBb[0], 0, C, am);
    for (int c = 0; c < NC; ++c) {
        int on = (c + 1 < NC);
        if (use_embq)
            fused_chunk<0, 0><<<32 + 4 * C, 1024, 0, stream>>>(
                words, xsrc0, wihq0f, wihq0b, b0f, b0b,
                preFb[(c + 1) & 1], preBb[(c + 1) & 1], (c + 1) * C, on,
                preFb[c & 1], preBb[c & 1], whh8_0f, whh8_0b, h1,
                wtag8, btag, emF, emB, stC, stH, c * C, C);
        else
            fused_chunk<0, 1><<<32 + 4 * C, 1024, 0, stream>>>(
                words, xsrc0, wihq0f, wihq0b, b0f, b0b,
                preFb[(c + 1) & 1], preBb[(c + 1) & 1], (c + 1) * C, on,
                preFb[c & 1], preBb[c & 1], whh8_0f, whh8_0b, h1,
                wtag8, btag, emF, emB, stC, stH, c * C, C);
    }
    // ---- layer 1 (fp8 A & B pregate) ----
    gemm_only1<<<4 * C, 1024, 0, stream>>>(nullptr, h1, wihq1f8, wihq1b8,
                                           b1f, b1b, preFb[0], preBb[0], 0, C);
    for (int c = 0; c < NC; ++c) {
        int on = (c + 1 < NC);
        fused_chunk<1, 2><<<32 + 4 * C, 1024, 0, stream>>>(
            nullptr, h1, wihq1f8, wihq1b8, b1f, b1b,
            preFb[(c + 1) & 1], preBb[(c + 1) & 1], (c + 1) * C, on,
            preFb[c & 1], preBb[c & 1], whh8_1f, whh8_1b, nullptr,
            wtag8, btag, emF, emB, stC, stH, c * C, C);
    }

    // ---- CRF: 4 half-chains, then join ----
    crf_half<<<512, 64, 0, stream>>>(emF, emB, trans,
                                     alph, betap, alphV, betaV, bpsW, npsW);
    crf_join<<<128, 64, 0, stream>>>(emF, emB, trans, labels,
                                     alph, betap, alphV, betaV, bpsW, npsW,
                                     diff, out + 1);
    nll_kernel<<<1, 128, 0, stream>>>(diff, out);
}

// Round 16
// 1725.872 us; speedup vs baseline: 1.2386x; 1.2386x over previous
//
#include <hip/hip_runtime.h>
#include <math.h>

#define T_LEN 512
#define BATCH 128
#define KTAG  32
#define START_TAG 30
#define END_TAG   31
#define NEGV  -100000.0f

#define L2E    1.4426950408889634f
#define TWOL2E 2.8853900817779268f
#define LN2    0.6931471805599453f

typedef __attribute__((ext_vector_type(4))) short bf16x4;
typedef __attribute__((ext_vector_type(8))) short bf16x8;
typedef __attribute__((ext_vector_type(4))) float f32x4;
#define MFMA16   __builtin_amdgcn_mfma_f32_16x16x32_bf16
#define MFMA16F8 __builtin_amdgcn_mfma_f32_16x16x32_fp8_fp8
#define EXP2(x)  __builtin_amdgcn_exp2f(x)
#define RCP(x)   __builtin_amdgcn_rcpf(x)

__device__ __forceinline__ short f2bf(float x) {   // RNE fp32->bf16
    unsigned int u = __float_as_uint(x);
    u += 0x7fffu + ((u >> 16) & 1u);
    return (short)(u >> 16);
}

__device__ __forceinline__ f32x4 bf4_to_f32x4(bf16x4 v) {
    union { bf16x4 s; uint2 u; } c; c.s = v;
    f32x4 r;
    r[0] = __uint_as_float(c.u.x << 16);
    r[1] = __uint_as_float(c.u.x & 0xffff0000u);
    r[2] = __uint_as_float(c.u.y << 16);
    r[3] = __uint_as_float(c.u.y & 0xffff0000u);
    return r;
}

// fp32 -> OCP e4m3fn, RNE, saturate. (HW-verified round 5.)
__device__ __forceinline__ unsigned char f2fp8(float x) {
    unsigned u = __float_as_uint(x);
    unsigned s = (u >> 24) & 0x80u;
    unsigned mag = u & 0x7fffffffu;
    if (mag >= 0x43e80000u) return (unsigned char)(s | 0x7e);
    int e = (int)(mag >> 23) - 127;
    int ulp_exp = (e < -6) ? -9 : (e - 3);
    float C = __uint_as_float((unsigned)((ulp_exp + 23 + 127) << 23)) * 1.5f;
    float r = (__uint_as_float(mag) + C) - C;
    unsigned ru = __float_as_uint(r);
    int re = (int)(ru >> 23) - 127;
    unsigned code;
    if (r == 0.0f) code = 0;
    else if (re < -6) code = (unsigned)(r * 512.0f);
    else code = (unsigned)((re + 7) << 3) | ((ru >> 20) & 7u);
    return (unsigned char)(s | code);
}

__device__ __forceinline__ unsigned pack2_fp8(float h0, float h1) {
#if __has_builtin(__builtin_amdgcn_cvt_pk_fp8_f32)
    return (unsigned)__builtin_amdgcn_cvt_pk_fp8_f32(h0, h1, 0, false);
#else
    return (unsigned)f2fp8(h0) | ((unsigned)f2fp8(h1) << 8);
#endif
}

__global__ void fill_kernel(float* out, int n, float v) {
    int i = blockIdx.x * 256 + threadIdx.x;
    if (i < n) out[i] = v;
}

// ---------------------------------------------------------------------------
// Pack helpers (HW-verified rounds 3-14; log2-domain gate scaling).
// ---------------------------------------------------------------------------
__device__ __forceinline__ void dev_pack_bf16(const float* __restrict__ W,
                                              short* __restrict__ out, int K, int idx) {
    const int KT = K >> 5;
    int i  = idx & 7;
    int ln = (idx >> 3) & 63;
    int rem = idx >> 9;
    int kt = rem % KT;
    int wt = rem / KT;
    int type = wt & 3, w = wt >> 2;
    int row = type * 256 + w * 16 + (ln & 15);
    int col = kt * 32 + ((ln >> 4) << 3) + i;
    float sc = (type == 2) ? TWOL2E : L2E;
    out[idx] = f2bf(W[(size_t)row * K + col] * sc);
}

__device__ __forceinline__ void dev_pack_fp8(const float* __restrict__ W,
                                             unsigned char* __restrict__ out, int K, int idx) {
    const int KT = K >> 5;
    int i  = idx & 7;
    int ln = (idx >> 3) & 63;
    int rem = idx >> 9;
    int kt = rem % KT;
    int wt = rem / KT;
    int type = wt & 3, w = wt >> 2;
    int row = type * 256 + w * 16 + (ln & 15);
    int col = kt * 32 + ((ln >> 4) << 3) + i;
    float sc = (type == 2) ? TWOL2E : L2E;
    out[idx] = f2fp8(W[(size_t)row * K + col] * sc);
}

__device__ __forceinline__ void dev_pack_wtag(const float* __restrict__ Wtag,
                                              unsigned char* __restrict__ out, int idx) {
    int i  = idx & 7;
    int ln = (idx >> 3) & 63;
    int kt = (idx >> 9) & 7;
    int nt = (idx >> 12) & 1;
    int dir = idx >> 13;
    int row = nt * 16 + (ln & 15);
    int col = dir * 256 + kt * 32 + ((ln >> 4) << 3) + i;
    out[idx] = f2fp8(Wtag[row * 512 + col]);
}

__global__ __launch_bounds__(256) void pack_all(
    const float* Wih0f, const float* Wih0b, const float* Wih1f, const float* Wih1b,
    const float* Whh0f, const float* Whh0b, const float* Whh1f, const float* Whh1b,
    const float* Wtag, const float* emb,
    short* wq0f, short* wq0b, unsigned char* wq1f8, unsigned char* wq1b8,
    unsigned char* h80f, unsigned char* h80b, unsigned char* h81f, unsigned char* h81b,
    unsigned char* wtag8, short* embq)
{
    const int bx = blockIdx.x;
    const int tid = threadIdx.x;
    if (bx < 2048) {
        const float* W = (bx < 1024) ? Wih0f : Wih0b;
        short* o = (bx < 1024) ? wq0f : wq0b;
        dev_pack_bf16(W, o, 256, (bx & 1023) * 256 + tid);
    } else if (bx < 6144) {
        const float* W = (bx < 4096) ? Wih1f : Wih1b;
        unsigned char* o = (bx < 4096) ? wq1f8 : wq1b8;
        dev_pack_fp8(W, o, 512, ((bx - 2048) & 2047) * 256 + tid);
    } else if (bx < 10240) {
        int seg = (bx - 6144) >> 10;
        const float* W = (seg == 0) ? Whh0f : (seg == 1) ? Whh0b : (seg == 2) ? Whh1f : Whh1b;
        unsigned char* o = (seg == 0) ? h80f : (seg == 1) ? h80b : (seg == 2) ? h81f : h81b;
        dev_pack_fp8(W, o, 256, ((bx - 6144) & 1023) * 256 + tid);
    } else if (bx < 10304) {
        dev_pack_wtag(Wtag, wtag8, (bx - 10240) * 256 + tid);
    } else {
        int i = (bx - 10304) * 256 + tid;
        embq[i] = f2bf(emb[i]);
    }
}

// ---------------------------------------------------------------------------
// Gemm role (HW-verified r9-14). LAYER 0: bf16 NT=2. LAYER 1: fp8 A/B NT=2.
// ---------------------------------------------------------------------------
template <int LAYER, int AMODE>
__device__ __forceinline__ void gemm_role(
    int gb, int C, const int* __restrict__ words, const void* __restrict__ Asrc,
    const void* __restrict__ BfF, const void* __restrict__ BfB,
    const float* __restrict__ bsF, const float* __restrict__ bsB,
    short* __restrict__ preF, short* __restrict__ preB, int s0, char* smraw)
{
    constexpr int K  = (LAYER == 0) ? 256 : 512;
    constexpr int KT = K / 32;
    constexpr int RB = (LAYER == 0) ? K * 2 : K;
    constexpr int NT = 2;
    constexpr int NH = 2;

    const int dir = gb / (NH * C);
    int rem = gb - dir * NH * C;
    const int half = rem / C;
    const int gx = rem - half * C;
    const int sblk = gx >> 3, bg = gx & 7;
    const int t0 = half * NT;
    const int tid = threadIdx.x;
    const int wv = tid >> 6, L = tid & 63;
    const int wid = wv;
    const int brow = L & 15, kgrp = L >> 4;

    const void* Bf = dir ? BfB : BfF;
    const float* bias = dir ? bsB : bsF;
    short* pre = dir ? preB : preF;
    char* lds = smraw;

    bf16x8 bw16[LAYER == 0 ? NT * KT : 1][1];
    long   bw8[LAYER == 1 ? NT * KT : 1];
    if (LAYER == 0) {
        const bf16x8* Bp = (const bf16x8*)Bf;
#pragma unroll
        for (int u = 0; u < NT; ++u)
#pragma unroll
            for (int kt = 0; kt < KT; ++kt)
                bw16[u * KT + kt][0] = Bp[(((wid * 4 + t0 + u) * KT + kt) << 6) + L];
    } else {
        const long* Bp = (const long*)Bf;
#pragma unroll
        for (int u = 0; u < NT; ++u)
#pragma unroll
            for (int kt = 0; kt < KT; ++kt)
                bw8[u * KT + kt] = Bp[(((wid * 4 + t0 + u) * KT + kt) << 6) + L];
    }

    float bb[NT];
#pragma unroll
    for (int u = 0; u < NT; ++u) {
        float sc = ((t0 + u) == 2) ? TWOL2E : L2E;
        bb[u] = bias[(t0 + u) * 256 + wid * 16 + brow] * sc;
    }

    for (int sl = 0; sl < 8; ++sl) {
        const int sloc = sblk * 8 + sl;
        const int t = dir ? (T_LEN - 1 - (s0 + sloc)) : (s0 + sloc);

        if (LAYER == 0) {
            if (tid < 512) {
                const int row = tid >> 5, ch = tid & 31;
                const int b = bg * 16 + row;
                const int cb = ch * 16;
                const int word = words[b * T_LEN + t];
                if (AMODE == 0) {
                    const char* src = (const char*)Asrc + (size_t)word * 512 + cb;
                    *(bf16x8*)(lds + ((row * RB + cb) ^ ((row & 7) << 4))) = *(const bf16x8*)src;
                } else {
                    const float* src = (const float*)Asrc + (size_t)word * 256 + ch * 8;
                    float4 f0 = *(const float4*)(src);
                    float4 f1 = *(const float4*)(src + 4);
                    short tmp[8] = {f2bf(f0.x), f2bf(f0.y), f2bf(f0.z), f2bf(f0.w),
                                    f2bf(f1.x), f2bf(f1.y), f2bf(f1.z), f2bf(f1.w)};
                    *(bf16x8*)(lds + ((row * RB + cb) ^ ((row & 7) << 4))) = *(const bf16x8*)tmp;
                }
            }
        } else {
            const int row = tid >> 6, ch = tid & 63;
            const int b = bg * 16 + row;
            const int cb = ch * 8;
            const unsigned char* src = (const unsigned char*)Asrc +
                                       ((size_t)t * BATCH + b) * 512 + cb;
            *(long*)(lds + ((row * RB + cb) ^ ((row & 7) << 3))) = *(const long*)src;
        }
        __syncthreads();

        f32x4 acc[NT];
#pragma unroll
        for (int u = 0; u < NT; ++u) acc[u] = (f32x4){bb[u], bb[u], bb[u], bb[u]};

#pragma unroll
        for (int kt = 0; kt < KT; ++kt) {
            if (LAYER == 0) {
                bf16x8 a = *(const bf16x8*)(lds + ((brow * RB + kt * 64 + kgrp * 16) ^ ((brow & 7) << 4)));
#pragma unroll
                for (int u = 0; u < NT; ++u)
                    acc[u] = MFMA16(a, bw16[u * KT + kt][0], acc[u], 0, 0, 0);
            } else {
                long a = *(const long*)(lds + ((brow * RB + kt * 32 + kgrp * 8) ^ ((brow & 7) << 3)));
#pragma unroll
                for (int u = 0; u < NT; ++u)
                    acc[u] = MFMA16F8(a, bw8[u * KT + kt], acc[u], 0, 0, 0);
            }
        }

        bf16x4* pp = (bf16x4*)pre;
        const size_t base = ((((size_t)sloc * 8 + bg) * 16 + wid) * 4 + t0) * 64 + L;
#pragma unroll
        for (int u = 0; u < NT; ++u) {
            bf16x4 o = {f2bf(acc[u][0]), f2bf(acc[u][1]), f2bf(acc[u][2]), f2bf(acc[u][3])};
            pp[base + (size_t)u * 64] = o;
        }
        __syncthreads();
    }
}

__global__ __launch_bounds__(1024) void gemm_only0(
    const int* words, const void* Asrc, const void* BfF, const void* BfB,
    const float* bsF, const float* bsB, short* preF, short* preB, int s0, int C, int amode)
{
    __shared__ __align__(16) char smraw[8192];
    if (amode == 0)
        gemm_role<0, 0>(blockIdx.x, C, words, Asrc, BfF, BfB, bsF, bsB, preF, preB, s0, smraw);
    else
        gemm_role<0, 1>(blockIdx.x, C, words, Asrc, BfF, BfB, bsF, bsB, preF, preB, s0, smraw);
}

__global__ __launch_bounds__(1024) void gemm_only1(
    const int* words, const void* Asrc, const void* BfF, const void* BfB,
    const float* bsF, const float* bsB, short* preF, short* preB, int s0, int C)
{
    __shared__ __align__(16) char smraw[8192];
    gemm_role<1, 2>(blockIdx.x, C, words, Asrc, BfF, BfB, bsF, bsB, preF, preB, s0, smraw);
}

// ---------------------------------------------------------------------------
// Fused chunk (HW-verified r9-14): blocks 0-31 = LSTM (M=8, split-layout,
// setprio(1) — latency-critical), blocks 32+ = pregate gemm for next chunk.
// Single 8-deep MFMA chain per gate (round-15 split REGRESSED; reverted).
// ---------------------------------------------------------------------------
template <int LAYER, int AMODE>
__global__ __launch_bounds__(1024) void fused_chunk(
    const int* __restrict__ words, const void* __restrict__ xsrc,
    const void* __restrict__ wihF, const void* __restrict__ wihB,
    const float* __restrict__ biasF, const float* __restrict__ biasB,
    short* __restrict__ preOutF, short* __restrict__ preOutB, int s0g, int gemm_on,
    const short* __restrict__ preF, const short* __restrict__ preB,
    const unsigned char* __restrict__ whhF, const unsigned char* __restrict__ whhB,
    unsigned char* __restrict__ h1out,
    const unsigned char* __restrict__ wtagf, const float* __restrict__ btag,
    float* __restrict__ emitF, float* __restrict__ emitB,
    float* __restrict__ stC, long* __restrict__ stH,
    int s0, int C)
{
    constexpr int SMB = (LAYER == 1) ? (8704 + 32768) : 8704;
    __shared__ __align__(16) char smraw[SMB];

    if (blockIdx.x >= 32) {
        if (gemm_on)
            gemm_role<LAYER, AMODE>(blockIdx.x - 32, C, words, xsrc, wihF, wihB,
                                    biasF, biasB, preOutF, preOutB, s0g, smraw);
        return;
    }

    // lstm waves carry the serial dependency chain: boost their CU priority
    __builtin_amdgcn_s_setprio(1);

    const int dir  = blockIdx.x >> 4;
    const int bg   = (blockIdx.x >> 1) & 7;
    const int half = blockIdx.x & 1;
    const int tid = threadIdx.x;
    const int wid = tid >> 6;
    const int L   = tid & 63;
    const int brow = L & 15;
    const int kgrp = L >> 4;
    const int Lp = (L + half * 32) & 63;

    const bf16x4* pre = (const bf16x4*)(dir ? preB : preF);
    long* hb0 = (long*)smraw;
    long* hb1 = (long*)(smraw + 4352);
    float (*ep)[8][16][32] = (float(*)[8][16][32])(smraw + 8704);

    const long* Wp = (const long*)(dir ? whhB : whhF);
    long whh[32];
#pragma unroll
    for (int tt = 0; tt < 4; ++tt)
#pragma unroll
        for (int kt = 0; kt < 8; ++kt)
            whh[tt * 8 + kt] = Wp[(((wid * 4 + tt) * 8 + kt) << 6) + L];

    long wt0 = 0, wt1 = 0;
    if (LAYER == 1) {
        int kw = (wid < 8) ? wid : 7;
        const long* wtp = (const long*)wtagf;
        wt0 = wtp[(((dir * 2 + 0) * 8 + kw) << 6) + L];
        wt1 = wtp[(((dir * 2 + 1) * 8 + kw) << 6) + L];
    }

    float cs0, cs1;
    if (s0 == 0) {
        for (int q = tid; q < 544; q += 1024) hb0[q] = 0;
        cs0 = cs1 = 0.f;
    } else {
        for (int q = tid; q < 544; q += 1024)
            hb0[q] = stH[(size_t)blockIdx.x * 544 + q];
        float2 c2 = ((const float2*)stC)[blockIdx.x * 1024 + tid];
        cs0 = c2.x; cs1 = c2.y;
    }
    for (int q = tid; q < 544; q += 1024) hb1[q] = 0;
    __syncthreads();

    const size_t pstride = 8 * 16 * 4 * 64;
    const size_t pbase = (((size_t)bg * 16 + wid) * 4) * 64 + Lp;
    bf16x4 pc0 = pre[pbase + 0 * 64];
    bf16x4 pc1 = pre[pbase + 1 * 64];
    bf16x4 pc2 = pre[pbase + 2 * 64];
    bf16x4 pc3 = pre[pbase + 3 * 64];

    const int srcL = L & 31;
    const bool lo = (L < 32);
    const int rb = ((srcL >> 4) << 2) + (lo ? 0 : 2);
    const int jj = wid * 16 + (L & 15);

    for (int s = s0; s < s0 + C; ++s) {
        const int sloc = s - s0;
        const int par = s & 1;
        const char* ldsr = (const char*)(par ? hb1 : hb0);
        char* ldsw = (char*)(par ? hb0 : hb1);

        f32x4 acc0 = bf4_to_f32x4(pc0);
        f32x4 acc1 = bf4_to_f32x4(pc1);
        f32x4 acc2 = bf4_to_f32x4(pc2);
        f32x4 acc3 = bf4_to_f32x4(pc3);

        {
            const int sl2 = (sloc + 1 < C) ? sloc + 1 : sloc;
            const size_t pb = (size_t)sl2 * pstride + pbase;
            pc0 = pre[pb + 0 * 64];
            pc1 = pre[pb + 1 * 64];
            pc2 = pre[pb + 2 * 64];
            pc3 = pre[pb + 3 * 64];
        }

#pragma unroll
        for (int kt = 0; kt < 8; ++kt) {
            long a = *(const long*)(ldsr + brow * 272 + kt * 32 + kgrp * 8);
            acc0 = MFMA16F8(a, whh[0 * 8 + kt], acc0, 0, 0, 0);
            acc1 = MFMA16F8(a, whh[1 * 8 + kt], acc1, 0, 0, 0);
            acc2 = MFMA16F8(a, whh[2 * 8 + kt], acc2, 0, 0, 0);
            acc3 = MFMA16F8(a, whh[3 * 8 + kt], acc3, 0, 0, 0);
        }

        if (LAYER == 1 && sloc >= 1 && wid < 8) {
            long a = *(const long*)(ldsr + brow * 272 + wid * 32 + kgrp * 8);
            f32x4 e0 = {0.f, 0.f, 0.f, 0.f}, e1 = {0.f, 0.f, 0.f, 0.f};
            e0 = MFMA16F8(a, wt0, e0, 0, 0, 0);
            e1 = MFMA16F8(a, wt1, e1, 0, 0, 0);
#pragma unroll
            for (int r = 0; r < 4; ++r) {
                int bl = (kgrp << 2) + r;
                ep[par][wid][bl][brow] = e0[r];
                ep[par][wid][bl][16 + brow] = e1[r];
            }
        }

        if (LAYER == 1 && sloc >= 2 && tid < 256) {
            int bl = tid >> 5, tg = tid & 31;
            float v = 0.f;
#pragma unroll
            for (int p = 0; p < 8; ++p) v += ep[par ^ 1][p][bl][tg];
            const int x = s - 2;
            const int tp = dir ? (T_LEN - 1 - x) : x;
            size_t ei = ((size_t)tp * BATCH + bg * 16 + half * 8 + bl) * KTAG + tg;
            if (dir == 0) emitF[ei] = v + btag[tg];
            else          emitB[ei] = v;
        }

        float g0v0, g0v1, g1v0, g1v1, g2v0, g2v1, g3v0, g3v1;
        {
            float a00 = __shfl(acc0[2], srcL), a01 = __shfl(acc0[3], srcL);
            float a10 = __shfl(acc1[2], srcL), a11 = __shfl(acc1[3], srcL);
            float a20 = __shfl(acc2[2], srcL), a21 = __shfl(acc2[3], srcL);
            float a30 = __shfl(acc3[2], srcL), a31 = __shfl(acc3[3], srcL);
            g0v0 = lo ? acc0[0] : a00;  g0v1 = lo ? acc0[1] : a01;
            g1v0 = lo ? acc1[0] : a10;  g1v1 = lo ? acc1[1] : a11;
            g2v0 = lo ? acc2[0] : a20;  g2v1 = lo ? acc2[1] : a21;
            g3v0 = lo ? acc3[0] : a30;  g3v1 = lo ? acc3[1] : a31;
        }

        float hh0, hh1;
        {
            float ig, fg, gg, og;
            ig = RCP(1.0f + EXP2(-g0v0)); fg = RCP(1.0f + EXP2(-g1v0));
            gg = 1.0f - 2.0f * RCP(1.0f + EXP2(g2v0));
            og = RCP(1.0f + EXP2(-g3v0));
            cs0 = fg * cs0 + ig * gg;
            hh0 = og * (1.0f - 2.0f * RCP(1.0f + EXP2(TWOL2E * cs0)));
            ig = RCP(1.0f + EXP2(-g0v1)); fg = RCP(1.0f + EXP2(-g1v1));
            gg = 1.0f - 2.0f * RCP(1.0f + EXP2(g2v1));
            og = RCP(1.0f + EXP2(-g3v1));
            cs1 = fg * cs1 + ig * gg;
            hh1 = og * (1.0f - 2.0f * RCP(1.0f + EXP2(TWOL2E * cs1)));
        }

        {
            unsigned pk = pack2_fp8(hh0, hh1);
            ldsw[(rb + 0) * 272 + jj] = (char)(pk);
            ldsw[(rb + 1) * 272 + jj] = (char)(pk >> 8);
            if (LAYER == 0) {
                const int t = dir ? (T_LEN - 1 - s) : s;
                size_t gb = ((size_t)t * BATCH + bg * 16 + half * 8 + rb) * 512 + dir * 256 + jj;
                h1out[gb]       = (unsigned char)pk;
                h1out[gb + 512] = (unsigned char)(pk >> 8);
            }
        }
        __syncthreads();
    }

    if (LAYER == 1) {
        if (wid < 8) {
            const char* ldsr = (const char*)hb0;
            long a = *(const long*)(ldsr + brow * 272 + wid * 32 + kgrp * 8);
            f32x4 e0 = {0.f, 0.f, 0.f, 0.f}, e1 = {0.f, 0.f, 0.f, 0.f};
            e0 = MFMA16F8(a, wt0, e0, 0, 0, 0);
            e1 = MFMA16F8(a, wt1, e1, 0, 0, 0);
#pragma unroll
            for (int r = 0; r < 4; ++r) {
                int bl = (kgrp << 2) + r;
                ep[0][wid][bl][brow] = e0[r];
                ep[0][wid][bl][16 + brow] = e1[r];
            }
        }
        if (tid < 256) {
            int bl = tid >> 5, tg = tid & 31;
            float v = 0.f;
#pragma unroll
            for (int p = 0; p < 8; ++p) v += ep[1][p][bl][tg];
            const int x = s0 + C - 2;
            const int tp = dir ? (T_LEN - 1 - x) : x;
            size_t ei = ((size_t)tp * BATCH + bg * 16 + half * 8 + bl) * KTAG + tg;
            if (dir == 0) emitF[ei] = v + btag[tg];
            else          emitB[ei] = v;
        }
        __syncthreads();
        if (tid < 256) {
            int bl = tid >> 5, tg = tid & 31;
            float v = 0.f;
#pragma unroll
            for (int p = 0; p < 8; ++p) v += ep[0][p][bl][tg];
            const int x = s0 + C - 1;
            const int tp = dir ? (T_LEN - 1 - x) : x;
            size_t ei = ((size_t)tp * BATCH + bg * 16 + half * 8 + bl) * KTAG + tg;
            if (dir == 0) emitF[ei] = v + btag[tg];
            else          emitB[ei] = v;
        }
    }

    for (int q = tid; q < 544; q += 1024)
        stH[(size_t)blockIdx.x * 544 + q] = hb0[q];
    ((float2*)stC)[blockIdx.x * 1024 + tid] = (float2){cs0, cs1};
    __builtin_amdgcn_s_setprio(0);
}

// ---------------------------------------------------------------------------
// CRF (HW-verified rounds 12-14): forward-backward split, 4 roles x 128.
// ---------------------------------------------------------------------------
__global__ __launch_bounds__(64) void crf_half(
    const float* __restrict__ emitF, const float* __restrict__ emitB,
    const float* __restrict__ trans,
    float* __restrict__ alph, float* __restrict__ betap,
    float* __restrict__ alphV, float* __restrict__ betaV,
    unsigned char* __restrict__ bpsW, unsigned char* __restrict__ npsW)
{
    const int lane = threadIdx.x;
    const int k = lane & 31;
    const int h = lane >> 5;
    const int p0 = h << 4;
    const int role = blockIdx.x >> 7;
    const int b = blockIdx.x & 127;

    __shared__ unsigned char ptr_l[256 * KTAG];

    if (role == 0) {
        float trow2[16];
#pragma unroll
        for (int i = 0; i < 4; ++i) {
            float4 f = *(const float4*)(trans + k * KTAG + p0 + i * 4);
            trow2[i * 4 + 0] = f.x * L2E; trow2[i * 4 + 1] = f.y * L2E;
            trow2[i * 4 + 2] = f.z * L2E; trow2[i * 4 + 3] = f.w * L2E;
        }
        float dp = (k == START_TAG) ? 0.0f : NEGV * L2E;
        size_t e0i = (size_t)b * KTAG + k;
        float e2 = (emitF[e0i] + emitB[e0i]) * L2E;

        for (int t = 0; t < 256; ++t) {
            float e_next2 = 0.0f;
            if (t + 1 < 256) {
                size_t ei = ((size_t)(t + 1) * BATCH + b) * KTAG + k;
                e_next2 = (emitF[ei] + emitB[ei]) * L2E;
            }
            float v[16];
#pragma unroll
            for (int q = 0; q < 16; ++q)
                v[q] = trow2[q] + __shfl(dp, p0 + q);
            float mx[8];
#pragma unroll
            for (int i = 0; i < 8; ++i) mx[i] = fmaxf(v[i], v[i + 8]);
#pragma unroll
            for (int i = 0; i < 4; ++i) mx[i] = fmaxf(mx[i], mx[i + 4]);
            float halfm = fmaxf(fmaxf(mx[0], mx[1]), fmaxf(mx[2], mx[3]));
            float m = fmaxf(halfm, __shfl_xor(halfm, 32));
            float es[16];
#pragma unroll
            for (int i = 0; i < 16; ++i) es[i] = EXP2(v[i] - m);
#pragma unroll
            for (int i = 0; i < 8; ++i) es[i] += es[i + 8];
#pragma unroll
            for (int i = 0; i < 4; ++i) es[i] += es[i + 4];
            float shalf = (es[0] + es[1]) + (es[2] + es[3]);
            float ssum = shalf + __shfl_xor(shalf, 32);
            dp = e2 + m + __log2f(ssum);
            e2 = e_next2;
        }
        if (lane < 32) alph[b * KTAG + k] = dp;
    } else if (role == 1) {
        float trowT2[16];
#pragma unroll
        for (int i = 0; i < 16; ++i)
            trowT2[i] = trans[(p0 + i) * KTAG + k] * L2E;
        float beta = trans[END_TAG * KTAG + k] * L2E;
        size_t e0i = ((size_t)511 * BATCH + b) * KTAG + k;
        float e2 = (emitF[e0i] + emitB[e0i]) * L2E;

        for (int it = 0; it < 256; ++it) {
            const int t = 510 - it;
            float e_next2 = 0.0f;
            if (it + 1 < 256) {
                size_t ei = ((size_t)t * BATCH + b) * KTAG + k;
                e_next2 = (emitF[ei] + emitB[ei]) * L2E;
            }
            float z = beta + e2;
            float v[16];
#pragma unroll
            for (int q = 0; q < 16; ++q)
                v[q] = trowT2[q] + __shfl(z, p0 + q);
            float mx[8];
#pragma unroll
            for (int i = 0; i < 8; ++i) mx[i] = fmaxf(v[i], v[i + 8]);
#pragma unroll
            for (int i = 0; i < 4; ++i) mx[i] = fmaxf(mx[i], mx[i + 4]);
            float halfm = fmaxf(fmaxf(mx[0], mx[1]), fmaxf(mx[2], mx[3]));
            float m = fmaxf(halfm, __shfl_xor(halfm, 32));
            float es[16];
#pragma unroll
            for (int i = 0; i < 16; ++i) es[i] = EXP2(v[i] - m);
#pragma unroll
            for (int i = 0; i < 8; ++i) es[i] += es[i + 8];
#pragma unroll
            for (int i = 0; i < 4; ++i) es[i] += es[i + 4];
            float shalf = (es[0] + es[1]) + (es[2] + es[3]);
            float ssum = shalf + __shfl_xor(shalf, 32);
            beta = m + __log2f(ssum);
            e2 = e_next2;
        }
        if (lane < 32) betap[b * KTAG + k] = beta;
    } else if (role == 2) {
        float trow[16];
#pragma unroll
        for (int i = 0; i < 4; ++i) {
            float4 f = *(const float4*)(trans + k * KTAG + p0 + i * 4);
            trow[i * 4 + 0] = f.x; trow[i * 4 + 1] = f.y;
            trow[i * 4 + 2] = f.z; trow[i * 4 + 3] = f.w;
        }
        float dpv = (k == START_TAG) ? 0.0f : NEGV;
        size_t e0i = (size_t)b * KTAG + k;
        float e = emitF[e0i] + emitB[e0i];

        for (int t = 0; t < 256; ++t) {
            float e_next = 0.0f;
            if (t + 1 < 256) {
                size_t ei = ((size_t)(t + 1) * BATCH + b) * KTAG + k;
                e_next = emitF[ei] + emitB[ei];
            }
            float w[16];
#pragma unroll
            for (int q = 0; q < 16; ++q)
                w[q] = trow[q] + __shfl(dpv, p0 + q);
            float bv_[8]; int bi_[8];
#pragma unroll
            for (int i = 0; i < 8; ++i) {
                bool g = w[2 * i + 1] > w[2 * i];
                bv_[i] = g ? w[2 * i + 1] : w[2 * i];
                bi_[i] = p0 + (g ? 2 * i + 1 : 2 * i);
            }
#pragma unroll
            for (int i = 0; i < 4; ++i) {
                bool g = bv_[2 * i + 1] > bv_[2 * i];
                bv_[i] = g ? bv_[2 * i + 1] : bv_[2 * i];
                bi_[i] = g ? bi_[2 * i + 1] : bi_[2 * i];
            }
            { bool g = bv_[3] > bv_[2]; bv_[1] = g ? bv_[3] : bv_[2]; bi_[1] = g ? bi_[3] : bi_[2]; }
            { bool g = bv_[1] > bv_[0]; bv_[0] = g ? bv_[1] : bv_[0]; bi_[0] = g ? bi_[1] : bi_[0]; }
            float ov = __shfl_xor(bv_[0], 32);
            int   oi = __shfl_xor(bi_[0], 32);
            bool g2 = h ? (ov >= bv_[0]) : (ov > bv_[0]);
            float bm  = g2 ? ov : bv_[0];
            int  barg = g2 ? oi : bi_[0];
            dpv = e + bm;
            if (!h) ptr_l[t * KTAG + k] = (unsigned char)barg;
            e = e_next;
        }
        if (lane < 32) alphV[b * KTAG + k] = dpv;
        for (int i = lane; i < 2048; i += 64)
            ((unsigned*)bpsW)[(size_t)b * 2048 + i] = ((const unsigned*)ptr_l)[i];
    } else {
        float trowT[16];
#pragma unroll
        for (int i = 0; i < 16; ++i)
            trowT[i] = trans[(p0 + i) * KTAG + k];
        float bvv = trans[END_TAG * KTAG + k];
        size_t e0i = ((size_t)511 * BATCH + b) * KTAG + k;
        float e = emitF[e0i] + emitB[e0i];

        for (int it = 0; it < 256; ++it) {
            const int t = 510 - it;
            float e_next = 0.0f;
            if (it + 1 < 256) {
                size_t ei = ((size_t)t * BATCH + b) * KTAG + k;
                e_next = emitF[ei] + emitB[ei];
            }
            float z = bvv + e;
            float w[16];
#pragma unroll
            for (int q = 0; q < 16; ++q)
                w[q] = trowT[q] + __shfl(z, p0 + q);
            float bv_[8]; int bi_[8];
#pragma unroll
            for (int i = 0; i < 8; ++i) {
                bool g = w[2 * i + 1] > w[2 * i];
                bv_[i] = g ? w[2 * i + 1] : w[2 * i];
                bi_[i] = p0 + (g ? 2 * i + 1 : 2 * i);
            }
#pragma unroll
            for (int i = 0; i < 4; ++i) {
                bool g = bv_[2 * i + 1] > bv_[2 * i];
                bv_[i] = g ? bv_[2 * i + 1] : bv_[2 * i];
                bi_[i] = g ? bi_[2 * i + 1] : bi_[2 * i];
            }
            { bool g = bv_[3] > bv_[2]; bv_[1] = g ? bv_[3] : bv_[2]; bi_[1] = g ? bi_[3] : bi_[2]; }
            { bool g = bv_[1] > bv_[0]; bv_[0] = g ? bv_[1] : bv_[0]; bi_[0] = g ? bi_[1] : bi_[0]; }
            float ov = __shfl_xor(bv_[0], 32);
            int   oi = __shfl_xor(bi_[0], 32);
            bool g2 = h ? (ov >= bv_[0]) : (ov > bv_[0]);
            float bm  = g2 ? ov : bv_[0];
            int  barg = g2 ? oi : bi_[0];
            bvv = bm;
            if (!h) ptr_l[(t - 255) * KTAG + k] = (unsigned char)barg;
            e = e_next;
        }
        if (lane < 32) betaV[b * KTAG + k] = bvv;
        for (int i = lane; i < 2048; i += 64)
            ((unsigned*)npsW)[(size_t)b * 2048 + i] = ((const unsigned*)ptr_l)[i];
    }
}

__global__ __launch_bounds__(64) void crf_join(
    const float* __restrict__ emitF, const float* __restrict__ emitB,
    const float* __restrict__ trans, const int* __restrict__ labels,
    const float* __restrict__ alph, const float* __restrict__ betap,
    const float* __restrict__ alphV, const float* __restrict__ betaV,
    const unsigned char* __restrict__ bpsW, const unsigned char* __restrict__ npsW,
    float* __restrict__ diff, float* __restrict__ path_out)
{
    const int b = blockIdx.x;
    const int lane = threadIdx.x;
    const int k = lane & 31;

    __shared__ unsigned char bps_l[256 * KTAG];
    __shared__ unsigned char nps_l[256 * KTAG];
    __shared__ unsigned char pth[T_LEN];

    for (int i = lane; i < 2048; i += 64) {
        ((unsigned*)bps_l)[i] = ((const unsigned*)bpsW)[(size_t)b * 2048 + i];
        ((unsigned*)nps_l)[i] = ((const unsigned*)npsW)[(size_t)b * 2048 + i];
    }

    float fv = alph[b * KTAG + k] + betap[b * KTAG + k];
    float mm = fv;
    for (int off = 16; off; off >>= 1) mm = fmaxf(mm, __shfl_xor(mm, off));
    float contrib = (lane < KTAG) ? EXP2(fv - mm) : 0.0f;
    float ss = contrib;
    for (int off = 32; off; off >>= 1) ss += __shfl_xor(ss, off);
    float logZ = (mm + __log2f(ss)) * LN2;

    float gsum = 0.0f;
    for (int t = lane; t < T_LEN; t += 64) {
        int curl = labels[b * T_LEN + t];
        int prev = (t > 0) ? labels[b * T_LEN + t - 1] : START_TAG;
        size_t gi = ((size_t)t * BATCH + b) * KTAG + curl;
        gsum += trans[curl * KTAG + prev] + emitF[gi] + emitB[gi];
    }
    if (lane == 0) gsum += trans[END_TAG * KTAG + labels[b * T_LEN + T_LEN - 1]];
    for (int off = 32; off; off >>= 1) gsum += __shfl_xor(gsum, off);

    float av = alphV[b * KTAG + k] + betaV[b * KTAG + k];
    int bi = k;
    for (int off = 16; off; off >>= 1) {
        float ovv = __shfl_xor(av, off);
        int   oii = __shfl_xor(bi, off);
        if (ovv > av || (ovv == av && oii < bi)) { av = ovv; bi = oii; }
    }

    __syncthreads();
    if (lane == 0) {
        diff[b] = logZ - gsum;
        int pb = bi, pf = bi;
        pth[255] = (unsigned char)bi;
        for (int i = 1; i <= 256; ++i) {
            if (i <= 255) {
                pb = bps_l[(256 - i) * KTAG + pb];
                pth[255 - i] = (unsigned char)pb;
            }
            pf = nps_l[(i - 1) * KTAG + pf];
            pth[255 + i] = (unsigned char)pf;
        }
    }
    __syncthreads();
    for (int t = lane; t < T_LEN; t += 64)
        path_out[(size_t)b * T_LEN + t] = (float)pth[t];
}

__global__ void nll_kernel(const float* __restrict__ diff, float* __restrict__ out) {
    int lane = threadIdx.x;   // 128
    float v = diff[lane];
    __shared__ float red[2];
    for (int off = 32; off; off >>= 1) v += __shfl_xor(v, off);
    if ((lane & 63) == 0) red[lane >> 6] = v;
    __syncthreads();
    if (lane == 0) out[0] = (red[0] + red[1]) / 128.0f;
}

// ---------------------------------------------------------------------------
extern "C" void kernel_launch(void* const* d_in, const int* in_sizes, int n_in,
                              void* d_out, int out_size, void* d_ws, size_t ws_size,
                              hipStream_t stream) {
    (void)in_sizes; (void)n_in;

    const int*   words  = (const int*)d_in[0];
    const int*   labels = (const int*)d_in[1];
    const float* emb    = (const float*)d_in[2];
    const float* Wih0f  = (const float*)d_in[3];
    const float* Whh0f  = (const float*)d_in[4];
    const float* b0f    = (const float*)d_in[5];
    const float* Wih0b  = (const float*)d_in[6];
    const float* Whh0b  = (const float*)d_in[7];
    const float* b0b    = (const float*)d_in[8];
    const float* Wih1f  = (const float*)d_in[9];
    const float* Whh1f  = (const float*)d_in[10];
    const float* b1f    = (const float*)d_in[11];
    const float* Wih1b  = (const float*)d_in[12];
    const float* Whh1b  = (const float*)d_in[13];
    const float* b1b    = (const float*)d_in[14];
    const float* Wtag   = (const float*)d_in[15];
    const float* btag   = (const float*)d_in[16];
    const float* trans  = (const float*)d_in[17];
    float* out = (float*)d_out;
    char* ws = (char*)d_ws;

    const size_t WIH0B = (size_t)1024 * 256 * 2;            // 512 KB (bf16)
    const size_t WIH1B = (size_t)1024 * 512;                // 512 KB (fp8)
    const size_t WHH8B = (size_t)1024 * 256;                // 256 KB
    const size_t WTAG8 = (size_t)16384;                     // 16 KB
    const size_t H1B   = (size_t)T_LEN * BATCH * 512;       // 33.6 MB (fp8)
    const size_t EMITB = (size_t)T_LEN * BATCH * KTAG * 4;  // 8.39 MB
    const size_t EMBQB = (size_t)30000 * 256 * 2;           // 15.36 MB
    const size_t STHB  = (size_t)32 * 544 * 8;              // 139 KB
    const size_t STCB  = (size_t)32 * 1024 * 8;             // 256 KB
    const size_t PSTEP = (size_t)BATCH * 1024 * 2;          // 0.262 MB/step/dir
    const size_t CRFAB = (size_t)4 * 128 * 32 * 4;          // 64 KB
    const size_t BPSB  = (size_t)128 * 256 * 32;            // 1 MB each

    const size_t base0 = 2 * WIH0B + 2 * WIH1B + 4 * WHH8B + WTAG8 + H1B +
                         2 * EMITB + STHB + STCB + CRFAB + 2 * BPSB +
                         4096 + (1u << 20);

    // prefer C=128: shortest serial gemm prologue while keeping chunk overlap
    const int cand[5] = {128, 256, 64, 32, 16};
    int C = 0, use_embq = 0;
    for (int eq = 1; eq >= 0 && !C; --eq)
        for (int ci = 0; ci < 5 && !C; ++ci) {
            int c = cand[ci];
            if (base0 + (eq ? EMBQB : 0) + 4 * (size_t)c * PSTEP <= ws_size) {
                C = c; use_embq = eq;
            }
        }
    if (!C) {
        fill_kernel<<<(out_size + 255) / 256, 256, 0, stream>>>(
            out, out_size, (float)(ws_size >> 20));
        return;
    }

    size_t off = 0;
    auto alloc = [&](size_t bytes) -> char* {
        char* p = ws + off;
        off = (off + bytes + 255) & ~(size_t)255;
        return p;
    };
    short* wihq0f = (short*)alloc(WIH0B);
    short* wihq0b = (short*)alloc(WIH0B);
    unsigned char* wihq1f8 = (unsigned char*)alloc(WIH1B);
    unsigned char* wihq1b8 = (unsigned char*)alloc(WIH1B);
    unsigned char* whh8_0f = (unsigned char*)alloc(WHH8B);
    unsigned char* whh8_0b = (unsigned char*)alloc(WHH8B);
    unsigned char* whh8_1f = (unsigned char*)alloc(WHH8B);
    unsigned char* whh8_1b = (unsigned char*)alloc(WHH8B);
    unsigned char* wtag8   = (unsigned char*)alloc(WTAG8);
    unsigned char* h1      = (unsigned char*)alloc(H1B);
    float* emF    = (float*)alloc(EMITB);
    float* emB    = (float*)alloc(EMITB);
    long*  stH    = (long*)alloc(STHB);
    float* stC    = (float*)alloc(STCB);
    float* diff   = (float*)alloc(4096);
    float* crfa   = (float*)alloc(CRFAB);
    unsigned char* bpsW = (unsigned char*)alloc(BPSB);
    unsigned char* npsW = (unsigned char*)alloc(BPSB);
    short* preFb[2], * preBb[2];
    preFb[0] = (short*)alloc((size_t)C * PSTEP);
    preFb[1] = (short*)alloc((size_t)C * PSTEP);
    preBb[0] = (short*)alloc((size_t)C * PSTEP);
    preBb[1] = (short*)alloc((size_t)C * PSTEP);
    short* embq = use_embq ? (short*)alloc(EMBQB) : nullptr;

    float* alph  = crfa;
    float* betap = crfa + 128 * 32;
    float* alphV = crfa + 2 * 128 * 32;
    float* betaV = crfa + 3 * 128 * 32;

    // ---- single pack launch ----
    {
        int nblk = 10304 + (use_embq ? 30000 : 0);
        pack_all<<<nblk, 256, 0, stream>>>(
            Wih0f, Wih0b, Wih1f, Wih1b, Whh0f, Whh0b, Whh1f, Whh1b, Wtag, emb,
            wihq0f, wihq0b, wihq1f8, wihq1b8,
            whh8_0f, whh8_0b, whh8_1f, whh8_1b, wtag8, embq);
    }

    const int NC = T_LEN / C;
    const void* xsrc0 = use_embq ? (const void*)embq : (const void*)emb;
    const int am = use_embq ? 0 : 1;

    // ---- layer 0 ----
    gemm_only0<<<4 * C, 1024, 0, stream>>>(words, xsrc0, wihq0f, wihq0b,
                                           b0f, b0b, preFb[0], preBb[0], 0, C, am);
    for (int c = 0; c < NC; ++c) {
        int on = (c + 1 < NC);
        if (use_embq)
            fused_chunk<0, 0><<<32 + 4 * C, 1024, 0, stream>>>(
                words, xsrc0, wihq0f, wihq0b, b0f, b0b,
                preFb[(c + 1) & 1], preBb[(c + 1) & 1], (c + 1) * C, on,
                preFb[c & 1], preBb[c & 1], whh8_0f, whh8_0b, h1,
                wtag8, btag, emF, emB, stC, stH, c * C, C);
        else
            fused_chunk<0, 1><<<32 + 4 * C, 1024, 0, stream>>>(
                words, xsrc0, wihq0f, wihq0b, b0f, b0b,
                preFb[(c + 1) & 1], preBb[(c + 1) & 1], (c + 1) * C, on,
                preFb[c & 1], preBb[c & 1], whh8_0f, whh8_0b, h1,
                wtag8, btag, emF, emB, stC, stH, c * C, C);
    }
    // ---- layer 1 (fp8 A & B pregate) ----
    gemm_only1<<<4 * C, 1024, 0, stream>>>(nullptr, h1, wihq1f8, wihq1b8,
                                           b1f, b1b, preFb[0], preBb[0], 0, C);
    for (int c = 0; c < NC; ++c) {
        int on = (c + 1 < NC);
        fused_chunk<1, 2><<<32 + 4 * C, 1024, 0, stream>>>(
            nullptr, h1, wihq1f8, wihq1b8, b1f, b1b,
            preFb[(c + 1) & 1], preBb[(c + 1) & 1], (c + 1) * C, on,
            preFb[c & 1], preBb[c & 1], whh8_1f, whh8_1b, nullptr,
            wtag8, btag, emF, emB, stC, stH, c * C, C);
    }

    // ---- CRF: 4 half-chains, then join ----
    crf_half<<<512, 64, 0, stream>>>(emF, emB, trans,
                                     alph, betap, alphV, betaV, bpsW, npsW);
    crf_join<<<128, 64, 0, stream>>>(emF, emB, trans, labels,
                                     alph, betap, alphV, betaV, bpsW, npsW,
                                     diff, out + 1);
    nll_kernel<<<1, 128, 0, stream>>>(diff, out);
}